// Round 8
// baseline (55.880 us; speedup 1.0000x reference)
//
#include <hip/hip_runtime.h>

#define TWO_PI_F 6.283185307179586f

// Problem constants (from setup_inputs)
#define C_O   512
#define C_CIN 512
#define C_K   16
#define C_KS  7
#define C_NI  16
#define C_NO  16

#define OUT0_SIZE (C_O * C_NI * C_CIN * C_NO)   // 67,108,864
#define OUT1_SIZE (C_O * C_NO * C_KS * C_KS)    // 401,408

// LDS row stride: 16 data + 1 wrap-dup + 1 pad = 18 floats. 18c mod 32 spreads
// 16 consecutive rows over 16 distinct (even) banks; 8B-aligned float2 staging.
#define SW_STRIDE 18

#define NBLOCKS 4096          // C_O * 2 (c-half) * 4 (ni-group); 4 full generations
#define BILIN_PER_BLOCK 98    // OUT1_SIZE / 4096 exactly

typedef float f32x4 __attribute__((ext_vector_type(4)));

// ---------------------------------------------------------------------------
// 4096 blocks x 512 threads (4 blocks/CU, 4 exact generations).
// Each block: stage 256 weight rows (16 KB LDS) -> 2 bursts of 4 back-to-back
// f32x4 stores per thread (64 KB/block, every wave-store 1 KB contiguous)
// -> 98-element bilinear tail (4096 x 98 = OUT1_SIZE exactly).
// ---------------------------------------------------------------------------
__global__ __launch_bounds__(512, 8) void fused_kernel(
    const float* __restrict__ in_H,
    const float* __restrict__ out_H,
    const float* __restrict__ weight_H,
    const float* __restrict__ weight,
    const float* __restrict__ grid_Rn,
    const float* __restrict__ mask,
    float* __restrict__ out0,
    float* __restrict__ out1)
{
    __shared__ float s_w[256 * SW_STRIDE];     // 18,432 B
    __shared__ float s_t[64];

    const int tid = threadIdx.x;
    const int bid = blockIdx.x;

    // ---- interp: bid = o*8 + ch*4 + nig ----
    const int o   = bid >> 3;
    const int ch  = (bid >> 2) & 1;            // c half: c = ch*256 + [0,256)
    const int nig = bid & 3;                   // ni group: ni = nig*4 + ni_l

    // t coordinate for this block's 4 ni x 16 no
    if (tid < 64) {
        int ni_l = tid >> 4;
        int no   = tid & 15;
        float x = in_H[nig * 4 + ni_l] - out_H[no];
        float r = fmodf(x, TWO_PI_F);
        if (r < 0.0f) r += TWO_PI_F;
        s_t[tid] = r * (16.0f / TWO_PI_F);
    }

    // Stage weight_H[o, ch*256 .. +255, :] (16 KB) into LDS, stride 18 + dup
    const float4* wsrc = reinterpret_cast<const float4*>(weight_H)
                       + (size_t)o * 2048 + ch * 1024;
#pragma unroll
    for (int j = 0; j < 2; ++j) {
        int f = j * 512 + tid;                 // float4 index: c_local = f/4
        float4 v = wsrc[f];
        int c    = f >> 2;
        int part = f & 3;
        float* row = &s_w[c * SW_STRIDE + part * 4];
        reinterpret_cast<float2*>(row)[0] = make_float2(v.x, v.y);
        reinterpret_cast<float2*>(row)[1] = make_float2(v.z, v.w);
        if (part == 0) s_w[c * SW_STRIDE + 16] = v.x;   // wrap duplicate
    }
    __syncthreads();

    const int q    = tid & 3;                  // no quad: no = q*4 + e
    const int crow = tid >> 2;                 // 0..127
    const float* wv0 = &s_w[crow * SW_STRIDE];
    const float* wv1 = &s_w[(128 + crow) * SW_STRIDE];
    f32x4* obase = reinterpret_cast<f32x4*>(out0)
                 + ((size_t)((o << 4) + (nig << 2)) << 11) + (ch << 10) + tid;

#pragma unroll
    for (int pair = 0; pair < 2; ++pair) {     // ni_l = pair*2 + {0,1}
        int   i0a[4], i0b[4];
        float fa[4],  fb[4];
#pragma unroll
        for (int e = 0; e < 4; ++e) {
            float ta = s_t[(pair * 2 + 0) * 16 + q * 4 + e];
            float fl = floorf(ta);
            i0a[e] = ((int)fl) & 15;  fa[e] = ta - fl;
            float tb = s_t[(pair * 2 + 1) * 16 + q * 4 + e];
            float fl2 = floorf(tb);
            i0b[e] = ((int)fl2) & 15; fb[e] = tb - fl2;
        }
        // Compute 4 results fully, then issue 4 back-to-back stores.
        f32x4 r00, r01, r10, r11;
        r00.x = (1.0f - fa[0]) * wv0[i0a[0]] + fa[0] * wv0[i0a[0] + 1];
        r00.y = (1.0f - fa[1]) * wv0[i0a[1]] + fa[1] * wv0[i0a[1] + 1];
        r00.z = (1.0f - fa[2]) * wv0[i0a[2]] + fa[2] * wv0[i0a[2] + 1];
        r00.w = (1.0f - fa[3]) * wv0[i0a[3]] + fa[3] * wv0[i0a[3] + 1];
        r01.x = (1.0f - fa[0]) * wv1[i0a[0]] + fa[0] * wv1[i0a[0] + 1];
        r01.y = (1.0f - fa[1]) * wv1[i0a[1]] + fa[1] * wv1[i0a[1] + 1];
        r01.z = (1.0f - fa[2]) * wv1[i0a[2]] + fa[2] * wv1[i0a[2] + 1];
        r01.w = (1.0f - fa[3]) * wv1[i0a[3]] + fa[3] * wv1[i0a[3] + 1];
        r10.x = (1.0f - fb[0]) * wv0[i0b[0]] + fb[0] * wv0[i0b[0] + 1];
        r10.y = (1.0f - fb[1]) * wv0[i0b[1]] + fb[1] * wv0[i0b[1] + 1];
        r10.z = (1.0f - fb[2]) * wv0[i0b[2]] + fb[2] * wv0[i0b[2] + 1];
        r10.w = (1.0f - fb[3]) * wv0[i0b[3]] + fb[3] * wv0[i0b[3] + 1];
        r11.x = (1.0f - fb[0]) * wv1[i0b[0]] + fb[0] * wv1[i0b[0] + 1];
        r11.y = (1.0f - fb[1]) * wv1[i0b[1]] + fb[1] * wv1[i0b[1] + 1];
        r11.z = (1.0f - fb[2]) * wv1[i0b[2]] + fb[2] * wv1[i0b[2] + 1];
        r11.w = (1.0f - fb[3]) * wv1[i0b[3]] + fb[3] * wv1[i0b[3] + 1];
        obase[(pair * 2 + 0) * 2048      ] = r00;   // 4 back-to-back 1 KB/wave
        obase[(pair * 2 + 0) * 2048 + 512] = r01;
        obase[(pair * 2 + 1) * 2048      ] = r10;
        obase[(pair * 2 + 1) * 2048 + 512] = r11;
    }

    // ---- bilinear tail: 98 out1 elements per block ----
    if (tid < BILIN_PER_BLOCK) {
        int idx = bid * BILIN_PER_BLOCK + tid;
        int pix = idx % 49;                    // ky*7 + kx
        int no  = (idx / 49) & 15;
        int oo  = idx / (49 * 16);

        float gx = grid_Rn[pix * 2 + 0];
        float gy = grid_Rn[pix * 2 + 1];

        float ang = -out_H[no];
        float sn, cs;
        sincosf(ang, &sn, &cs);

        float x = cs * gx - sn * gy;
        float y = sn * gx + cs * gy;

        float X = (x + 1.0f) * 3.0f;           // align_corners map to [0,6]
        float Y = (y + 1.0f) * 3.0f;

        float x0f = floorf(X), y0f = floorf(Y);
        float wx = X - x0f,    wy = Y - y0f;
        int   x0 = (int)x0f,   y0 = (int)y0f;

        const float* img = weight + oo * 49;

        auto gat = [&](int yy, int xx) -> float {
            bool v = (yy >= 0) & (yy < 7) & (xx >= 0) & (xx < 7);
            int yc = min(max(yy, 0), 6);
            int xc = min(max(xx, 0), 6);
            float val = img[yc * 7 + xc];
            return v ? val : 0.0f;
        };

        float r = (1.0f - wy) * (1.0f - wx) * gat(y0,     x0)
                + (1.0f - wy) * wx          * gat(y0,     x0 + 1)
                + wy          * (1.0f - wx) * gat(y0 + 1, x0)
                + wy          * wx          * gat(y0 + 1, x0 + 1);

        out1[idx] = mask[pix] * r;
    }
}

extern "C" void kernel_launch(void* const* d_in, const int* in_sizes, int n_in,
                              void* d_out, int out_size, void* d_ws, size_t ws_size,
                              hipStream_t stream) {
    const float* in_H     = (const float*)d_in[0];
    const float* out_H    = (const float*)d_in[1];
    const float* weight_H = (const float*)d_in[2];
    const float* weight   = (const float*)d_in[3];
    // d_in[4] = grid_H (implicit in uniform-grid formula), unused
    const float* grid_Rn  = (const float*)d_in[5];
    const float* mask     = (const float*)d_in[6];

    float* out0 = (float*)d_out;
    float* out1 = out0 + OUT0_SIZE;

    hipLaunchKernelGGL(fused_kernel, dim3(NBLOCKS), dim3(512), 0, stream,
                       in_H, out_H, weight_H, weight, grid_Rn, mask, out0, out1);
}